// Round 9
// baseline (105.058 us; speedup 1.0000x reference)
//
#include <hip/hip_runtime.h>
#include <hip/hip_bf16.h>
#include <math.h>

// (B, L, H, C) = (2, 512, 128, 25)
#define BB 2
#define LL 512
#define HH 128
#define CC 25
#define W4H (4*HH)

typedef __attribute__((ext_vector_type(4))) float    f32x4;
typedef __attribute__((ext_vector_type(8))) _Float16 half8;
typedef __attribute__((ext_vector_type(2))) _Float16 half2t;
typedef __attribute__((ext_vector_type(4))) unsigned uint4v;

#define MTILE 64    // m rows per block (4 waves x 16)
#define LPB   8     // l rows per block
#define XPH   136   // f16 LDS pitch in halves (272 B rows)

static __device__ __forceinline__ half8 habs8(half8 x) {
    uint4v u = __builtin_bit_cast(uint4v, x);
    u &= 0x7FFF7FFFu;
    return __builtin_bit_cast(half8, u);
}
static __device__ __forceinline__ half2t pkrtz(float a, float b) {
    return __builtin_bit_cast(half2t, __builtin_amdgcn_cvt_pkrtz(a, b));
}
union H4 { half2t h2[2]; unsigned long long u64; };
union H8 { half2t h2[4]; uint4v u4; half8 h8; };

// Load one B-fragment (8 f16) for output-col c, W columns [col0, col0+8).
// W is row-major [C][512]; c >= CC -> zero fragment.
static __device__ __forceinline__ half8 loadWfrag(const float* __restrict__ W,
                                                  int c, int col0) {
    H8 h; h.u4 = (uint4v){0u, 0u, 0u, 0u};
    if (c < CC) {
        const float* p = W + (size_t)c * W4H + col0;
        const f32x4 v0 = *(const f32x4*)(p);
        const f32x4 v1 = *(const f32x4*)(p + 4);
        h.h2[0] = pkrtz(v0[0], v0[1]);
        h.h2[1] = pkrtz(v0[2], v0[3]);
        h.h2[2] = pkrtz(v1[0], v1[1]);
        h.h2[3] = pkrtz(v1[2], v1[3]);
    }
    return h.h8;
}

// Single fused kernel, no workspace.
// Main features per (l,m): k in [0,256): k<128 -> x1*x2 (W3, col 256+k);
// k>=128 -> |x1-x2| (W4, col 384+(k-128) = 256+k).  t1 = x1.W1 (+bias) via
// wave-0 MFMA into LDS; t2 = x2.W2 via per-wave MFMA staying in registers.
__global__ __launch_bounds__(256)
void biaffine_fused(const float* __restrict__ x1, const float* __restrict__ x2,
                    const float* __restrict__ W, const float* __restrict__ bias,
                    float* __restrict__ out)
{
    __shared__ __align__(16) _Float16 x1h[LPB * XPH];   // 2176 B
    __shared__ __align__(16) float    t1s[LPB * 32];    // 1024 B  (t1 + bias)

    const int tid = threadIdx.x;
    const int b   = blockIdx.z;
    const int l0  = blockIdx.y * LPB;
    const int m0  = blockIdx.x * MTILE;

    const int lane = tid & 63;
    const int wv   = tid >> 6;      // wave 0..3
    const int q    = lane >> 4;     // k-group 0..3
    const int cn   = lane & 15;     // A-row (m) / D-col (c)

    // ---- stage x1 rows (8 x 128) f32 -> f16 into LDS ----
    {
        const float* sx1 = x1 + ((size_t)b * LL + l0) * HH;
        const int r  = tid >> 5;               // 0..7
        const int c4 = tid & 31;
        const f32x4 v = *(const f32x4*)(sx1 + r * HH + c4 * 4);
        H4 h;
        h.h2[0] = pkrtz(v[0], v[1]);
        h.h2[1] = pkrtz(v[2], v[3]);
        *(unsigned long long*)(&x1h[r * XPH + c4 * 4]) = h.u64;
    }
    __syncthreads();

    // ---- X2f: this lane's x2 fragments straight from global (L2-hot) ----
    const int mrowA = wv * 16 + cn;
    half8 X2f[4];
    {
        const float* px2 = x2 + ((size_t)b * LL + m0 + mrowA) * HH;
        #pragma unroll
        for (int hh = 0; hh < 4; ++hh) {
            const float* p = px2 + hh * 32 + q * 8;
            const f32x4 v0 = *(const f32x4*)(p);
            const f32x4 v1 = *(const f32x4*)(p + 4);
            H8 h;
            h.h2[0] = pkrtz(v0[0], v0[1]);
            h.h2[1] = pkrtz(v0[2], v0[3]);
            h.h2[2] = pkrtz(v1[0], v1[1]);
            h.h2[3] = pkrtz(v1[2], v1[3]);
            X2f[hh] = h.h8;
        }
    }

    // ---- t2 = x2 . W2 via MFMA (per wave; result lives in the exact lanes needed) ----
    f32x4 t2a = {0.f,0.f,0.f,0.f}, t2b = {0.f,0.f,0.f,0.f};
    #pragma unroll
    for (int kk = 0; kk < 4; ++kk) {
        const int col0 = HH + kk * 32 + q * 8;           // W2 block
        const half8 b0 = loadWfrag(W, cn,      col0);
        const half8 b1 = loadWfrag(W, cn + 16, col0);
        t2a = __builtin_amdgcn_mfma_f32_16x16x32_f16(X2f[kk], b0, t2a, 0, 0, 0);
        t2b = __builtin_amdgcn_mfma_f32_16x16x32_f16(X2f[kk], b1, t2b, 0, 0, 0);
    }

    // ---- t1 = x1 . W1 (+bias) via MFMA on wave 0 only -> LDS bounce ----
    if (wv == 0) {
        f32x4 t1acc0 = {0.f,0.f,0.f,0.f}, t1acc1 = {0.f,0.f,0.f,0.f};
        #pragma unroll
        for (int kk = 0; kk < 4; ++kk) {
            // A-row i holds x1 row (i&7): lane cn supplies row cn&7
            const half8 a1 = *(const half8*)(&x1h[(cn & 7) * XPH + kk * 32 + q * 8]);
            const int col0 = kk * 32 + q * 8;            // W1 block
            const half8 b0 = loadWfrag(W, cn,      col0);
            const half8 b1 = loadWfrag(W, cn + 16, col0);
            t1acc0 = __builtin_amdgcn_mfma_f32_16x16x32_f16(a1, b0, t1acc0, 0, 0, 0);
            t1acc1 = __builtin_amdgcn_mfma_f32_16x16x32_f16(a1, b1, t1acc1, 0, 0, 0);
        }
        if (q < 2) {
            const float ba = bias[cn];
            const float bb = (cn + 16 < CC) ? bias[cn + 16] : 0.f;
            #pragma unroll
            for (int r = 0; r < 4; ++r) {
                const int l = q * 4 + r;                 // 0..7
                t1s[l * 32 + cn]      = t1acc0[r] + ba;
                t1s[l * 32 + 16 + cn] = t1acc1[r] + bb;
            }
        }
    }

    // ---- persistent main B fragments (W3|W4 -> col 256+k), from global (L2-hot) ----
    half8 Bf0[8], Bf1[8];
    #pragma unroll
    for (int kk = 0; kk < 8; ++kk) {
        const int col0 = 2 * HH + kk * 32 + q * 8;
        Bf0[kk] = loadWfrag(W, cn,      col0);
        Bf1[kk] = loadWfrag(W, cn + 16, col0);
    }
    __syncthreads();                                     // t1s ready

    const bool cok = (cn + 16 < CC);

    // ---- main loop: per l, 16 MFMA over K=256 (2 indep acc chains), per-l epilogue ----
    #pragma unroll
    for (int l = 0; l < LPB; ++l) {
        f32x4 acc0 = {0.f,0.f,0.f,0.f};
        f32x4 acc1 = {0.f,0.f,0.f,0.f};

        #pragma unroll
        for (int hh = 0; hh < 4; ++hh) {
            const half8 a  = *(const half8*)(&x1h[l * XPH + hh * 32 + q * 8]); // broadcast
            const half8 bq = X2f[hh];
            const half8 Ap = a * bq;
            const half8 Ad = habs8(a - bq);
            acc0 = __builtin_amdgcn_mfma_f32_16x16x32_f16(Ap, Bf0[hh],     acc0, 0, 0, 0);
            acc1 = __builtin_amdgcn_mfma_f32_16x16x32_f16(Ap, Bf1[hh],     acc1, 0, 0, 0);
            acc0 = __builtin_amdgcn_mfma_f32_16x16x32_f16(Ad, Bf0[4 + hh], acc0, 0, 0, 0);
            acc1 = __builtin_amdgcn_mfma_f32_16x16x32_f16(Ad, Bf1[4 + hh], acc1, 0, 0, 0);
        }

        const int lg = l0 + l;
        const float t1a = t1s[l * 32 + cn];              // broadcast reads
        const float t1b = t1s[l * 32 + 16 + cn];
        float* obase = out + (((size_t)b * LL + lg) * LL + (m0 + wv * 16 + q * 4)) * CC + cn;
        #pragma unroll
        for (int r = 0; r < 4; ++r) {
            obase[(size_t)r * CC] = acc0[r] + t1a + t2a[r];
            if (cok) obase[(size_t)r * CC + 16] = acc1[r] + t1b + t2b[r];
        }
    }
}

extern "C" void kernel_launch(void* const* d_in, const int* in_sizes, int n_in,
                              void* d_out, int out_size, void* d_ws, size_t ws_size,
                              hipStream_t stream) {
    const float* x1   = (const float*)d_in[0];
    const float* x2   = (const float*)d_in[1];
    const float* W    = (const float*)d_in[2];
    const float* bias = (const float*)d_in[3];
    float* out = (float*)d_out;

    dim3 grid(LL / MTILE, LL / LPB, BB);    // (8, 64, 2) = 1024 blocks
    biaffine_fused<<<grid, 256, 0, stream>>>(x1, x2, W, bias, out);
}

// Round 10
// 90.234 us; speedup vs baseline: 1.1643x; 1.1643x over previous
//
#include <hip/hip_runtime.h>
#include <hip/hip_bf16.h>
#include <math.h>

// (B, L, H, C) = (2, 512, 128, 25)
#define BB 2
#define LL 512
#define HH 128
#define CC 25
#define W4H (4*HH)

typedef __attribute__((ext_vector_type(4))) float    f32x4;
typedef __attribute__((ext_vector_type(8))) _Float16 half8;
typedef __attribute__((ext_vector_type(2))) _Float16 half2t;
typedef __attribute__((ext_vector_type(4))) unsigned uint4v;

#define MTILE 64    // m rows per block (4 waves x 16)
#define LPB   8     // l rows per block

#define NFRAG 2048
#define WS_X_OFF (NFRAG*8)       // halves: W table first (16384 halves = 32 KB)
#define XELS (BB*LL*HH)          // 131072 halves per x array

static __device__ __forceinline__ half8 habs8(half8 x) {
    uint4v u = __builtin_bit_cast(uint4v, x);
    u &= 0x7FFF7FFFu;
    return __builtin_bit_cast(half8, u);
}
static __device__ __forceinline__ half2t pkrtz(float a, float b) {
    return __builtin_bit_cast(half2t, __builtin_amdgcn_cvt_pkrtz(a, b));
}
union H4 { half2t h2[2]; unsigned long long u64; };
union H8 { half2t h2[4]; uint4v u4; half8 h8; };

// W fragment table (R8-verified layout): fid = (kk*2 + t)*64 + lane, 8 halves.
// lane=(q<<4)|cn: c = cn + 16*t ; k-slot k0 = kk*32 + q*8 ; W col wc = (k0+256)&511.
//   kk 0..7  : wc in [256,512) = W3|W4  (main features x1*x2 , |x1-x2|)
//   kk 8..11 : wc in [0,128)   = W1     (t1)
//   kk 12..15: wc in [128,256) = W2     (t2)
__global__ __launch_bounds__(256)
void pack_kernel(const float* __restrict__ x1, const float* __restrict__ x2,
                 const float* __restrict__ W, _Float16* __restrict__ ws)
{
    const int gid = blockIdx.x * 256 + threadIdx.x;     // 0..4095 (16 blocks)

    // ---- W fragments (first 2048 threads) ----
    if (gid < NFRAG) {
        const int ln  = gid & 63;
        const int t   = (gid >> 6) & 1;
        const int kk  = gid >> 7;
        const int c   = (ln & 15) + 16 * t;
        const int k0  = kk * 32 + ((ln >> 4) << 3);
        const int wc  = (k0 + 256) & 511;
        H8 h; h.u4 = (uint4v){0u, 0u, 0u, 0u};
        if (c < CC) {
            const float* p = W + (size_t)c * W4H + wc;
            const f32x4 v0 = *(const f32x4*)(p);
            const f32x4 v1 = *(const f32x4*)(p + 4);
            h.h2[0] = pkrtz(v0[0], v0[1]);
            h.h2[1] = pkrtz(v0[2], v0[3]);
            h.h2[2] = pkrtz(v1[0], v1[1]);
            h.h2[3] = pkrtz(v1[2], v1[3]);
        }
        *(uint4v*)(ws + (size_t)gid * 8) = h.u4;
    }

    // ---- x1/x2 -> f16 linear (32768 chunks of 8 elements) ----
    _Float16* wsX = ws + WS_X_OFF;
    #pragma unroll
    for (int i = 0; i < 8; ++i) {
        const int ch  = gid + i * 4096;                 // 0..32767
        const int arr = ch >> 14;                       // 0:x1 1:x2
        const int off = (ch & 16383) * 8;
        const float* src = (arr ? x2 : x1) + off;
        const f32x4 v0 = *(const f32x4*)(src);
        const f32x4 v1 = *(const f32x4*)(src + 4);
        H8 h;
        h.h2[0] = pkrtz(v0[0], v0[1]);
        h.h2[1] = pkrtz(v0[2], v0[3]);
        h.h2[2] = pkrtz(v1[0], v1[1]);
        h.h2[3] = pkrtz(v1[2], v1[3]);
        *(uint4v*)(wsX + (size_t)ch * 8) = h.u4;
    }
}

__global__ __launch_bounds__(256)
void biaffine_fused(const _Float16* __restrict__ ws, const float* __restrict__ bias,
                    float* __restrict__ out)
{
    __shared__ __align__(16) _Float16 x1h[LPB * HH];    // 2048 B
    __shared__ __align__(16) float    t1s[LPB * 32];    // 1024 B

    const int tid = threadIdx.x;
    const int b   = blockIdx.z;
    const int l0  = blockIdx.y * LPB;
    const int m0  = blockIdx.x * MTILE;

    const int lane = tid & 63;
    const int wv   = tid >> 6;      // wave 0..3
    const int q    = lane >> 4;     // k-group 0..3
    const int cn   = lane & 15;     // A-row (m) / D-col (c)

    const _Float16* wsWf = ws;
    const _Float16* x1p  = ws + WS_X_OFF;               // x1 f16 [B*L][128]
    const _Float16* x2p  = x1p + XELS;                  // x2 f16 [B*L][128]

    // ---- stage x1 rows (8 x 128 f16, pure copy, no converts) ----
    if (tid < 128)
        *(uint4v*)(&x1h[tid * 8]) =
            *(const uint4v*)(x1p + ((size_t)b * LL + l0) * HH + tid * 8);
    __syncthreads();

    // ---- X2f: pure f16 loads ----
    const int mrowA = wv * 16 + cn;
    const _Float16* px2 = x2p + ((size_t)b * LL + m0 + mrowA) * HH;
    half8 X2f[4];
    #pragma unroll
    for (int hh = 0; hh < 4; ++hh)
        X2f[hh] = *(const half8*)(px2 + hh * 32 + q * 8);

    // ---- persistent main B fragments (kk 0..7), contiguous 16B/lane ----
    half8 Bf0[8], Bf1[8];
    #pragma unroll
    for (int kk = 0; kk < 8; ++kk) {
        Bf0[kk] = *(const half8*)(wsWf + ((size_t)(kk * 2 + 0) * 64 + lane) * 8);
        Bf1[kk] = *(const half8*)(wsWf + ((size_t)(kk * 2 + 1) * 64 + lane) * 8);
    }

    // ---- t2 = x2 . W2 via MFMA (table kk = 12..15) ----
    f32x4 t2a = {0.f,0.f,0.f,0.f}, t2b = {0.f,0.f,0.f,0.f};
    #pragma unroll
    for (int kk = 0; kk < 4; ++kk) {
        const half8 b0 = *(const half8*)(wsWf + ((size_t)((12 + kk) * 2 + 0) * 64 + lane) * 8);
        const half8 b1 = *(const half8*)(wsWf + ((size_t)((12 + kk) * 2 + 1) * 64 + lane) * 8);
        t2a = __builtin_amdgcn_mfma_f32_16x16x32_f16(X2f[kk], b0, t2a, 0, 0, 0);
        t2b = __builtin_amdgcn_mfma_f32_16x16x32_f16(X2f[kk], b1, t2b, 0, 0, 0);
    }

    // ---- t1 = x1 . W1 (+bias) via MFMA on wave 0 (table kk = 8..11) -> LDS ----
    if (wv == 0) {
        f32x4 t1acc0 = {0.f,0.f,0.f,0.f}, t1acc1 = {0.f,0.f,0.f,0.f};
        #pragma unroll
        for (int kk = 0; kk < 4; ++kk) {
            const half8 a1 = *(const half8*)(&x1h[(cn & 7) * HH + kk * 32 + q * 8]);
            const half8 b0 = *(const half8*)(wsWf + ((size_t)((8 + kk) * 2 + 0) * 64 + lane) * 8);
            const half8 b1 = *(const half8*)(wsWf + ((size_t)((8 + kk) * 2 + 1) * 64 + lane) * 8);
            t1acc0 = __builtin_amdgcn_mfma_f32_16x16x32_f16(a1, b0, t1acc0, 0, 0, 0);
            t1acc1 = __builtin_amdgcn_mfma_f32_16x16x32_f16(a1, b1, t1acc1, 0, 0, 0);
        }
        if (q < 2) {
            const float ba = bias[cn];
            const float bb = (cn + 16 < CC) ? bias[cn + 16] : 0.f;
            #pragma unroll
            for (int r = 0; r < 4; ++r) {
                const int l = q * 4 + r;
                t1s[l * 32 + cn]      = t1acc0[r] + ba;
                t1s[l * 32 + 16 + cn] = t1acc1[r] + bb;
            }
        }
    }
    __syncthreads();                                    // t1s ready

    const bool cok = (cn + 16 < CC);

    // ---- main loop: per l, 16 MFMA over K=256 (2 indep chains), per-l epilogue ----
    #pragma unroll
    for (int l = 0; l < LPB; ++l) {
        f32x4 acc0 = {0.f,0.f,0.f,0.f};
        f32x4 acc1 = {0.f,0.f,0.f,0.f};

        #pragma unroll
        for (int hh = 0; hh < 4; ++hh) {
            const half8 a  = *(const half8*)(&x1h[l * HH + hh * 32 + q * 8]); // broadcast
            const half8 bq = X2f[hh];
            const half8 Ap = a * bq;
            const half8 Ad = habs8(a - bq);
            acc0 = __builtin_amdgcn_mfma_f32_16x16x32_f16(Ap, Bf0[hh],     acc0, 0, 0, 0);
            acc1 = __builtin_amdgcn_mfma_f32_16x16x32_f16(Ap, Bf1[hh],     acc1, 0, 0, 0);
            acc0 = __builtin_amdgcn_mfma_f32_16x16x32_f16(Ad, Bf0[4 + hh], acc0, 0, 0, 0);
            acc1 = __builtin_amdgcn_mfma_f32_16x16x32_f16(Ad, Bf1[4 + hh], acc1, 0, 0, 0);
        }

        const int lg = l0 + l;
        const float t1a = t1s[l * 32 + cn];
        const float t1b = t1s[l * 32 + 16 + cn];
        float* obase = out + (((size_t)b * LL + lg) * LL + (m0 + wv * 16 + q * 4)) * CC + cn;
        #pragma unroll
        for (int r = 0; r < 4; ++r) {
            obase[(size_t)r * CC] = acc0[r] + t1a + t2a[r];
            if (cok) obase[(size_t)r * CC + 16] = acc1[r] + t1b + t2b[r];
        }
    }
}

extern "C" void kernel_launch(void* const* d_in, const int* in_sizes, int n_in,
                              void* d_out, int out_size, void* d_ws, size_t ws_size,
                              hipStream_t stream) {
    const float* x1   = (const float*)d_in[0];
    const float* x2   = (const float*)d_in[1];
    const float* W    = (const float*)d_in[2];
    const float* bias = (const float*)d_in[3];
    float* out = (float*)d_out;
    _Float16* ws = (_Float16*)d_ws;

    pack_kernel<<<16, 256, 0, stream>>>(x1, x2, W, ws);

    dim3 grid(LL / MTILE, LL / LPB, BB);    // (8, 64, 2) = 1024 blocks
    biaffine_fused<<<grid, 256, 0, stream>>>(ws, bias, out);
}